// Round 1
// baseline (1308.764 us; speedup 1.0000x reference)
//
#include <hip/hip_runtime.h>
#include <hip/hip_bf16.h>

typedef __bf16 bf16;
typedef __attribute__((ext_vector_type(8))) __bf16 bf16x8;
typedef __attribute__((ext_vector_type(4))) float floatx4;

#define HEADS 16
#define NTOK 49
#define MROWS (2048 * 49)        // 100352
#define LOGIT_MAX 4.6051702f     // ln(100)

// ---------------- helpers ----------------

__device__ __forceinline__ void gload16(const void* g, void* l) {
  __builtin_amdgcn_global_load_lds((const __attribute__((address_space(1))) void*)g,
                                   (__attribute__((address_space(3))) void*)l, 16, 0, 0);
}

__device__ __forceinline__ void unpack8(uint4 raw, float* dst) {
  unsigned u[4] = {raw.x, raw.y, raw.z, raw.w};
#pragma unroll
  for (int q = 0; q < 4; ++q) {
    dst[2 * q]     = __builtin_bit_cast(float, u[q] << 16);
    dst[2 * q + 1] = __builtin_bit_cast(float, u[q] & 0xffff0000u);
  }
}

// ---------------- fp32 -> bf16 convert (vectorized) ----------------

__global__ void cvt_x(const float* __restrict__ in, bf16* __restrict__ out, int n4) {
  int i = blockIdx.x * blockDim.x + threadIdx.x;
  const int stride = gridDim.x * blockDim.x;
  typedef __attribute__((ext_vector_type(4))) __bf16 bf16x4;
  for (; i < n4; i += stride) {
    float4 v = ((const float4*)in)[i];
    bf16x4 o;
    o[0] = (bf16)v.x; o[1] = (bf16)v.y; o[2] = (bf16)v.z; o[3] = (bf16)v.w;
    *(bf16x4*)&out[(long)i * 4] = o;
  }
}

// out[c][r] = (bf16) in[r][c]   (weights -> B^T bf16)
__global__ void transpose_bf16(const float* __restrict__ in, bf16* __restrict__ out,
                               int R, int C) {
  int idx = blockIdx.x * blockDim.x + threadIdx.x;
  if (idx < R * C) {
    int r = idx / C, c = idx % C;
    out[(long)c * R + r] = (bf16)in[(long)r * C + c];
  }
}

// ---------------- CPB MLP: [169,2] -> relu([169,512]) -> [169,16] ----------------

__global__ void cpb_mlp(const float* __restrict__ w1, const float* __restrict__ b1,
                        const float* __restrict__ w2, float* __restrict__ out169) {
  const int r = blockIdx.x;          // 0..168
  const int ti = r / 13, tj = r % 13;
  float v0 = (float)(ti - 6) * (8.0f / 6.0f);
  float v1 = (float)(tj - 6) * (8.0f / 6.0f);
  float s0 = (v0 > 0.f) ? 1.f : ((v0 < 0.f) ? -1.f : 0.f);
  float s1 = (v1 > 0.f) ? 1.f : ((v1 < 0.f) ? -1.f : 0.f);
  const float t0 = s0 * log2f(fabsf(v0) + 1.0f) * (1.0f / 3.0f);  // log2(8)=3
  const float t1 = s1 * log2f(fabsf(v1) + 1.0f) * (1.0f / 3.0f);

  float acc[16];
#pragma unroll
  for (int h = 0; h < 16; ++h) acc[h] = 0.f;

  for (int c = threadIdx.x; c < 512; c += 64) {
    float hv = fmaxf(t0 * w1[c] + t1 * w1[512 + c] + b1[c], 0.f);
#pragma unroll
    for (int h = 0; h < 16; ++h) acc[h] += hv * w2[c * 16 + h];
  }
#pragma unroll
  for (int h = 0; h < 16; ++h) {
    float s = acc[h];
    for (int off = 32; off > 0; off >>= 1) s += __shfl_down(s, off);
    if (threadIdx.x == 0) out169[r * 16 + h] = s;
  }
}

// bias_sig[h][i][j] = 16*sigmoid(table169[idx(i,j)][h])
__global__ void bias_expand(const float* __restrict__ out169, float* __restrict__ bias_sig) {
  int idx = blockIdx.x * blockDim.x + threadIdx.x;
  if (idx < 16 * 2401) {
    int h = idx / 2401;
    int ij = idx % 2401;
    int i = ij / 49, j = ij % 49;
    int di = i / 7 - j / 7 + 6;
    int dj = i % 7 - j % 7 + 6;
    float v = out169[(di * 13 + dj) * 16 + h];
    bias_sig[idx] = 16.0f / (1.0f + expf(-v));
  }
}

// ---------------- bf16 MFMA GEMM, C = A[M,K] * BT[N,K]^T ----------------
// 128x128 tile, BK=64, 4 waves (2x2), 16x16x32 MFMA, global_load_lds width 16.
// EPI 0: bf16 out + qkv bias (q cols [0,512), v cols [1024,1536))
// EPI 1: fp32 out + proj bias

template <int EPI>
__global__ __launch_bounds__(256, 2)
void gemm_bt(const bf16* __restrict__ A, const bf16* __restrict__ BT,
             void* __restrict__ Cout,
             const float* __restrict__ bias0, const float* __restrict__ bias1,
             int M, int N, int K) {
  __shared__ bf16 Asl[128 * 64];
  __shared__ bf16 Bsl[128 * 64];
  const int tid = threadIdx.x;
  const int lane = tid & 63;
  const int wave = tid >> 6;
  const int wm = wave >> 1, wn = wave & 1;
  const long m0 = (long)blockIdx.x * 128;
  const long n0 = (long)blockIdx.y * 128;

  floatx4 acc[4][4] = {};

  const int r_l = lane >> 3;         // 0..7
  const int k_l = (lane & 7) << 3;   // 0..56
  const bf16* aB = A + m0 * K + k_l;
  const bf16* bB = BT + n0 * K + k_l;

  for (int kt = 0; kt < K; kt += 64) {
    __syncthreads();
#pragma unroll
    for (int i = 0; i < 4; ++i) {
      const int rbase = wave * 32 + i * 8;
      gload16(aB + (long)(rbase + r_l) * K + kt, &Asl[rbase * 64]);
      gload16(bB + (long)(rbase + r_l) * K + kt, &Bsl[rbase * 64]);
    }
    __syncthreads();
#pragma unroll
    for (int t = 0; t < 2; ++t) {
      const int kk = t * 32 + (lane >> 4) * 8;
      bf16x8 af[4], bfr[4];
#pragma unroll
      for (int m = 0; m < 4; ++m)
        af[m] = *(const bf16x8*)&Asl[(wm * 64 + m * 16 + (lane & 15)) * 64 + kk];
#pragma unroll
      for (int n = 0; n < 4; ++n)
        bfr[n] = *(const bf16x8*)&Bsl[(wn * 64 + n * 16 + (lane & 15)) * 64 + kk];
#pragma unroll
      for (int m = 0; m < 4; ++m)
#pragma unroll
        for (int n = 0; n < 4; ++n)
          acc[m][n] = __builtin_amdgcn_mfma_f32_16x16x32_bf16(af[m], bfr[n], acc[m][n], 0, 0, 0);
    }
  }

  const int rr = (lane >> 4) * 4;
  const int cc = lane & 15;
#pragma unroll
  for (int m = 0; m < 4; ++m) {
#pragma unroll
    for (int n = 0; n < 4; ++n) {
      const long col = n0 + wn * 64 + n * 16 + cc;
      float badd;
      if (EPI == 0)
        badd = (col < 512) ? bias0[col] : ((col >= 1024) ? bias1[col - 1024] : 0.0f);
      else
        badd = bias0[col];
#pragma unroll
      for (int r = 0; r < 4; ++r) {
        const long row = m0 + wm * 64 + m * 16 + rr + r;
        const float v = acc[m][n][r] + badd;
        if (EPI == 0)
          ((bf16*)Cout)[row * N + col] = (bf16)v;
        else
          ((float*)Cout)[row * N + col] = v;
      }
    }
  }
}

// ---------------- per-(b,h) window attention, 1 wave / block ----------------

__global__ __launch_bounds__(64)
void attn_win(const bf16* __restrict__ qkv, const float* __restrict__ bias_sig,
              const float* __restrict__ logit_scale, bf16* __restrict__ aout) {
  __shared__ float Q[NTOK * 32], Ks[NTOK * 32], Vs[NTOK * 32];
  __shared__ float S[NTOK * 52];
  __shared__ float rq[NTOK], rk[NTOK];
  const int lane = threadIdx.x;
  const int b = blockIdx.x >> 4;
  const int h = blockIdx.x & 15;
  const long base = (long)b * NTOK * 1536 + h * 32;

  for (int i = lane; i < NTOK * 4; i += 64) {
    const int row = i >> 2, part = (i & 3) * 8;
    const long off = base + (long)row * 1536 + part;
    unpack8(*(const uint4*)(qkv + off), &Q[row * 32 + part]);
    unpack8(*(const uint4*)(qkv + off + 512), &Ks[row * 32 + part]);
    unpack8(*(const uint4*)(qkv + off + 1024), &Vs[row * 32 + part]);
  }
  __syncthreads();

  if (lane < NTOK) {
    float sq = 0.f, sk = 0.f;
#pragma unroll
    for (int c = 0; c < 32; ++c) {
      float a = Q[lane * 32 + c]; sq += a * a;
      float k2 = Ks[lane * 32 + c]; sk += k2 * k2;
    }
    rq[lane] = rsqrtf(fmaxf(sq, 1e-12f));
    rk[lane] = rsqrtf(fmaxf(sk, 1e-12f));
  }
  __syncthreads();

  const float scale = __expf(fminf(logit_scale[h], LOGIT_MAX));
  const float* bh = bias_sig + h * 2401;
  for (int o = lane; o < 2401; o += 64) {
    const int i = o / 49, j = o - i * 49;
    float s = 0.f;
#pragma unroll
    for (int c = 0; c < 32; ++c) s += Q[i * 32 + c] * Ks[j * 32 + c];
    S[i * 52 + j] = s * rq[i] * rk[j] * scale + bh[o];
  }
  __syncthreads();

  if (lane < NTOK) {
    float mx = -1e30f;
    for (int j = 0; j < 49; ++j) mx = fmaxf(mx, S[lane * 52 + j]);
    float sum = 0.f;
    for (int j = 0; j < 49; ++j) {
      float e = __expf(S[lane * 52 + j] - mx);
      S[lane * 52 + j] = e;
      sum += e;
    }
    const float inv = 1.0f / sum;
    for (int j = 0; j < 49; ++j) S[lane * 52 + j] *= inv;
  }
  __syncthreads();

  const long obase = (long)b * NTOK * 512 + h * 32;
  for (int o = lane; o < NTOK * 32; o += 64) {
    const int i = o >> 5, dd = o & 31;
    float s = 0.f;
    for (int j = 0; j < 49; ++j) s += S[i * 52 + j] * Vs[j * 32 + dd];
    aout[obase + (long)i * 512 + dd] = (bf16)s;
  }
}

// ---------------- launch ----------------

extern "C" void kernel_launch(void* const* d_in, const int* in_sizes, int n_in,
                              void* d_out, int out_size, void* d_ws, size_t ws_size,
                              hipStream_t stream) {
  (void)in_sizes; (void)n_in; (void)out_size; (void)ws_size;
  const float* x           = (const float*)d_in[0];
  const float* w_qkv       = (const float*)d_in[1];
  const float* q_bias      = (const float*)d_in[2];
  const float* v_bias      = (const float*)d_in[3];
  const float* logit_scale = (const float*)d_in[4];
  const float* cpb_w1      = (const float*)d_in[5];
  const float* cpb_b1      = (const float*)d_in[6];
  const float* cpb_w2      = (const float*)d_in[7];
  const float* proj_w      = (const float*)d_in[8];
  const float* proj_b      = (const float*)d_in[9];
  float* out = (float*)d_out;

  char* ws = (char*)d_ws;
  const size_t QKV_B  = 308281344;   // 100352*1536*2
  const size_t XBF_B  = 102760448;   // 100352*512*2
  const size_t WQT_B  = 1572864;     // 1536*512*2
  const size_t PJT_B  = 524288;      // 512*512*2
  const size_t T169_B = 10816;       // 169*16*4
  bf16*  qkv      = (bf16*)ws;
  bf16*  xbf      = (bf16*)(ws + QKV_B);               // also attn_out (aliased)
  bf16*  wqkvT    = (bf16*)(ws + QKV_B + XBF_B);
  bf16*  projT    = (bf16*)(ws + QKV_B + XBF_B + WQT_B);
  float* tab169   = (float*)(ws + QKV_B + XBF_B + WQT_B + PJT_B);
  float* bias_sig = (float*)(ws + QKV_B + XBF_B + WQT_B + PJT_B + T169_B);

  cvt_x<<<2048, 256, 0, stream>>>(x, xbf, MROWS * 512 / 4);
  transpose_bf16<<<3072, 256, 0, stream>>>(w_qkv, wqkvT, 512, 1536);
  transpose_bf16<<<1024, 256, 0, stream>>>(proj_w, projT, 512, 512);
  cpb_mlp<<<169, 64, 0, stream>>>(cpb_w1, cpb_b1, cpb_w2, tab169);
  bias_expand<<<151, 256, 0, stream>>>(tab169, bias_sig);

  gemm_bt<0><<<dim3(784, 12), 256, 0, stream>>>(xbf, wqkvT, qkv, q_bias, v_bias,
                                                MROWS, 1536, 512);
  attn_win<<<32768, 64, 0, stream>>>(qkv, bias_sig, logit_scale, xbf);
  gemm_bt<1><<<dim3(784, 4), 256, 0, stream>>>(xbf, projT, out, proj_b, nullptr,
                                               MROWS, 512, 512);
}

// Round 2
// 570.903 us; speedup vs baseline: 2.2924x; 2.2924x over previous
//
#include <hip/hip_runtime.h>
#include <hip/hip_bf16.h>

typedef __bf16 bf16;
typedef __attribute__((ext_vector_type(8))) __bf16 bf16x8;
typedef __attribute__((ext_vector_type(4))) __bf16 bf16x4;
typedef __attribute__((ext_vector_type(4))) float floatx4;

#define HEADS 16
#define NTOK 49
#define MROWS (2048 * 49)        // 100352
#define LOGIT_MAX 4.6051702f     // ln(100)

// ---------------- helpers ----------------

__device__ __forceinline__ void gload16(const void* g, void* l) {
  __builtin_amdgcn_global_load_lds((const __attribute__((address_space(1))) void*)g,
                                   (__attribute__((address_space(3))) void*)l, 16, 0, 0);
}

// ---------------- fp32 -> bf16 convert (vectorized) ----------------

__global__ void cvt_x(const float* __restrict__ in, bf16* __restrict__ out, int n4) {
  int i = blockIdx.x * blockDim.x + threadIdx.x;
  const int stride = gridDim.x * blockDim.x;
  for (; i < n4; i += stride) {
    float4 v = ((const float4*)in)[i];
    bf16x4 o;
    o[0] = (bf16)v.x; o[1] = (bf16)v.y; o[2] = (bf16)v.z; o[3] = (bf16)v.w;
    *(bf16x4*)&out[(long)i * 4] = o;
  }
}

// out[c][r] = (bf16) in[r][c]   (weights -> B^T bf16)
__global__ void transpose_bf16(const float* __restrict__ in, bf16* __restrict__ out,
                               int R, int C) {
  int idx = blockIdx.x * blockDim.x + threadIdx.x;
  if (idx < R * C) {
    int r = idx / C, c = idx % C;
    out[(long)c * R + r] = (bf16)in[(long)r * C + c];
  }
}

// ---------------- CPB MLP: [169,2] -> relu([169,512]) -> [169,16] ----------------

__global__ void cpb_mlp(const float* __restrict__ w1, const float* __restrict__ b1,
                        const float* __restrict__ w2, float* __restrict__ out169) {
  const int r = blockIdx.x;          // 0..168
  const int ti = r / 13, tj = r % 13;
  float v0 = (float)(ti - 6) * (8.0f / 6.0f);
  float v1 = (float)(tj - 6) * (8.0f / 6.0f);
  float s0 = (v0 > 0.f) ? 1.f : ((v0 < 0.f) ? -1.f : 0.f);
  float s1 = (v1 > 0.f) ? 1.f : ((v1 < 0.f) ? -1.f : 0.f);
  const float t0 = s0 * log2f(fabsf(v0) + 1.0f) * (1.0f / 3.0f);  // log2(8)=3
  const float t1 = s1 * log2f(fabsf(v1) + 1.0f) * (1.0f / 3.0f);

  float acc[16];
#pragma unroll
  for (int h = 0; h < 16; ++h) acc[h] = 0.f;

  for (int c = threadIdx.x; c < 512; c += 64) {
    float hv = fmaxf(t0 * w1[c] + t1 * w1[512 + c] + b1[c], 0.f);
#pragma unroll
    for (int h = 0; h < 16; ++h) acc[h] += hv * w2[c * 16 + h];
  }
#pragma unroll
  for (int h = 0; h < 16; ++h) {
    float s = acc[h];
    for (int off = 32; off > 0; off >>= 1) s += __shfl_down(s, off);
    if (threadIdx.x == 0) out169[r * 16 + h] = s;
  }
}

// bias_sig: padded [16][64][52] fp32; [h][q][k] = 16*sigmoid(table[idx(q,k)][h]), 0 outside
__global__ void bias_expand(const float* __restrict__ out169, float* __restrict__ bias_sig) {
  int idx = blockIdx.x * blockDim.x + threadIdx.x;
  if (idx < 16 * 64 * 52) {
    int h = idx / 3328;
    int rem = idx % 3328;
    int q = rem / 52, k = rem % 52;
    float val = 0.f;
    if (q < 49 && k < 49) {
      int di = q / 7 - k / 7 + 6;
      int dj = q % 7 - k % 7 + 6;
      float v = out169[(di * 13 + dj) * 16 + h];
      val = 16.0f / (1.0f + expf(-v));
    }
    bias_sig[idx] = val;
  }
}

// ---------------- bf16 MFMA GEMM, C = A[M,K] * BT[N,K]^T ----------------

template <int EPI>
__global__ __launch_bounds__(256, 2)
void gemm_bt(const bf16* __restrict__ A, const bf16* __restrict__ BT,
             void* __restrict__ Cout,
             const float* __restrict__ bias0, const float* __restrict__ bias1,
             int M, int N, int K) {
  __shared__ bf16 Asl[128 * 64];
  __shared__ bf16 Bsl[128 * 64];
  const int tid = threadIdx.x;
  const int lane = tid & 63;
  const int wave = tid >> 6;
  const int wm = wave >> 1, wn = wave & 1;
  const long m0 = (long)blockIdx.x * 128;
  const long n0 = (long)blockIdx.y * 128;

  floatx4 acc[4][4] = {};

  const int r_l = lane >> 3;         // 0..7
  const int k_l = (lane & 7) << 3;   // 0..56
  const bf16* aB = A + m0 * K + k_l;
  const bf16* bB = BT + n0 * K + k_l;

  for (int kt = 0; kt < K; kt += 64) {
    __syncthreads();
#pragma unroll
    for (int i = 0; i < 4; ++i) {
      const int rbase = wave * 32 + i * 8;
      gload16(aB + (long)(rbase + r_l) * K + kt, &Asl[rbase * 64]);
      gload16(bB + (long)(rbase + r_l) * K + kt, &Bsl[rbase * 64]);
    }
    __syncthreads();
#pragma unroll
    for (int t = 0; t < 2; ++t) {
      const int kk = t * 32 + (lane >> 4) * 8;
      bf16x8 af[4], bfr[4];
#pragma unroll
      for (int m = 0; m < 4; ++m)
        af[m] = *(const bf16x8*)&Asl[(wm * 64 + m * 16 + (lane & 15)) * 64 + kk];
#pragma unroll
      for (int n = 0; n < 4; ++n)
        bfr[n] = *(const bf16x8*)&Bsl[(wn * 64 + n * 16 + (lane & 15)) * 64 + kk];
#pragma unroll
      for (int m = 0; m < 4; ++m)
#pragma unroll
        for (int n = 0; n < 4; ++n)
          acc[m][n] = __builtin_amdgcn_mfma_f32_16x16x32_bf16(af[m], bfr[n], acc[m][n], 0, 0, 0);
    }
  }

  const int rr = (lane >> 4) * 4;
  const int cc = lane & 15;
#pragma unroll
  for (int m = 0; m < 4; ++m) {
#pragma unroll
    for (int n = 0; n < 4; ++n) {
      const long col = n0 + wn * 64 + n * 16 + cc;
      float badd;
      if (EPI == 0)
        badd = (col < 512) ? bias0[col] : ((col >= 1024) ? bias1[col - 1024] : 0.0f);
      else
        badd = bias0[col];
#pragma unroll
      for (int r = 0; r < 4; ++r) {
        const long row = m0 + wm * 64 + m * 16 + rr + r;
        const float v = acc[m][n][r] + badd;
        if (EPI == 0)
          ((bf16*)Cout)[row * N + col] = (bf16)v;
        else
          ((float*)Cout)[row * N + col] = v;
      }
    }
  }
}

// ---------------- MFMA window attention: 1 wave per (b,h), 4 waves/block ----------------
// Computes S^T = mfma(K_frag, Q_frag) so each q-row's logits live in 4 lanes.
// P routed through per-wave XOR-swizzled LDS tile (no barriers needed).

__global__ __launch_bounds__(256)
void attn_mfma(const bf16* __restrict__ qkv, const float* __restrict__ bias_sig,
               const float* __restrict__ logit_scale, bf16* __restrict__ aout) {
  __shared__ __align__(16) bf16 Plds[4][16 * 72];
  const int tid = threadIdx.x;
  const int wave = tid >> 6, lane = tid & 63;
  const int l15 = lane & 15, g = lane >> 4;
  const int bh = blockIdx.x * 4 + wave;
  const int b = bh >> 4, h = bh & 15;
  const long base = (long)b * NTOK * 1536 + h * 32;
  const bf16* Qg = qkv + base;
  const bf16* Kg = qkv + base + 512;
  const bf16* Vg = qkv + base + 1024;
  bf16* P = Plds[wave];

  const float scale = __expf(fminf(logit_scale[h], LOGIT_MAX));

  // ---- K fragments, l2-normalized in-register ----
  bf16x8 kf[4];
#pragma unroll
  for (int kt = 0; kt < 4; ++kt) {
    const int row = kt * 16 + l15;
    bf16x8 raw = *(const bf16x8*)(Kg + (long)row * 1536 + g * 8);
    float fv[8], ss = 0.f;
#pragma unroll
    for (int j = 0; j < 8; ++j) { fv[j] = (float)raw[j]; ss += fv[j] * fv[j]; }
    ss += __shfl_xor(ss, 16);
    ss += __shfl_xor(ss, 32);
    const float rk = rsqrtf(fmaxf(ss, 1e-12f));
#pragma unroll
    for (int j = 0; j < 8; ++j) kf[kt][j] = (bf16)(fv[j] * rk);
  }

  // ---- V^T fragments via predicated scalar loads (L1-resident tile) ----
  bf16x8 vf[2][2];
#pragma unroll
  for (int dt = 0; dt < 2; ++dt)
#pragma unroll
    for (int t = 0; t < 2; ++t)
#pragma unroll
      for (int i = 0; i < 8; ++i) {
        const int k = t * 32 + g * 8 + i;
        vf[dt][t][i] = (k < NTOK) ? Vg[(long)k * 1536 + dt * 16 + l15] : (bf16)0.0f;
      }

  const floatx4 zero = {};
  const int swz = l15 & 3;

  for (int qt = 0; qt < 4; ++qt) {
    const int qrow = qt * 16 + l15;
    // Q fragment, normalized
    bf16x8 qraw = *(const bf16x8*)(Qg + (long)qrow * 1536 + g * 8);
    float fq[8], ssq = 0.f;
#pragma unroll
    for (int j = 0; j < 8; ++j) { fq[j] = (float)qraw[j]; ssq += fq[j] * fq[j]; }
    ssq += __shfl_xor(ssq, 16);
    ssq += __shfl_xor(ssq, 32);
    const float rq = rsqrtf(fmaxf(ssq, 1e-12f));
    bf16x8 qf;
#pragma unroll
    for (int j = 0; j < 8; ++j) qf[j] = (bf16)(fq[j] * rq);

    // bias rows (padded table, float4-aligned)
    float4 b4[4];
#pragma unroll
    for (int kt = 0; kt < 4; ++kt)
      b4[kt] = *(const float4*)(bias_sig + h * 3328 + qrow * 52 + kt * 16 + g * 4);

    // S^T tiles: lane holds S[q=l15][k=16*kt+4*g+reg]
    floatx4 st[4];
#pragma unroll
    for (int kt = 0; kt < 4; ++kt)
      st[kt] = __builtin_amdgcn_mfma_f32_16x16x32_bf16(kf[kt], qf, zero, 0, 0, 0);

    // softmax over k (49 valid), row spread across 4 lanes (xor 16/32)
    float sv[4][4];
    float m = -1e30f;
#pragma unroll
    for (int kt = 0; kt < 4; ++kt)
#pragma unroll
      for (int r = 0; r < 4; ++r) {
        const int k = kt * 16 + g * 4 + r;
        const float s = (k < NTOK) ? st[kt][r] * scale + ((const float*)&b4[kt])[r] : -1e30f;
        sv[kt][r] = s;
        m = fmaxf(m, s);
      }
    m = fmaxf(m, __shfl_xor(m, 16));
    m = fmaxf(m, __shfl_xor(m, 32));
    float l = 0.f;
#pragma unroll
    for (int kt = 0; kt < 4; ++kt)
#pragma unroll
      for (int r = 0; r < 4; ++r) {
        const float p = __expf(sv[kt][r] - m);
        sv[kt][r] = p;
        l += p;
      }
    l += __shfl_xor(l, 16);
    l += __shfl_xor(l, 32);
    const float inv = 1.0f / l;

    // store P (bf16) to swizzled LDS: logical col k -> granule (k/16)^(l15&3)
#pragma unroll
    for (int kt = 0; kt < 4; ++kt) {
      bf16x4 pk;
#pragma unroll
      for (int r = 0; r < 4; ++r) pk[r] = (bf16)(sv[kt][r] * inv);
      *(bf16x4*)&P[l15 * 72 + (kt ^ swz) * 16 + g * 4] = pk;
    }
    // read P as A-fragments: row q=l15, k = 32t + 8g + i
    bf16x8 ap[2];
#pragma unroll
    for (int t = 0; t < 2; ++t) {
      const int gran = (2 * t + (g >> 1)) ^ swz;
      ap[t] = *(const bf16x8*)&P[l15 * 72 + gran * 16 + (g & 1) * 8];
    }

    // PV
    floatx4 ot[2] = {};
#pragma unroll
    for (int dt = 0; dt < 2; ++dt)
#pragma unroll
      for (int t = 0; t < 2; ++t)
        ot[dt] = __builtin_amdgcn_mfma_f32_16x16x32_bf16(ap[t], vf[dt][t], ot[dt], 0, 0, 0);

    // store O rows q = qt*16 + 4g + r
#pragma unroll
    for (int dt = 0; dt < 2; ++dt)
#pragma unroll
      for (int r = 0; r < 4; ++r) {
        const int qg2 = qt * 16 + g * 4 + r;
        if (qg2 < NTOK)
          aout[(long)b * NTOK * 512 + (long)qg2 * 512 + h * 32 + dt * 16 + l15] =
              (bf16)ot[dt][r];
      }
  }
}

// ---------------- launch ----------------

extern "C" void kernel_launch(void* const* d_in, const int* in_sizes, int n_in,
                              void* d_out, int out_size, void* d_ws, size_t ws_size,
                              hipStream_t stream) {
  (void)in_sizes; (void)n_in; (void)out_size; (void)ws_size;
  const float* x           = (const float*)d_in[0];
  const float* w_qkv       = (const float*)d_in[1];
  const float* q_bias      = (const float*)d_in[2];
  const float* v_bias      = (const float*)d_in[3];
  const float* logit_scale = (const float*)d_in[4];
  const float* cpb_w1      = (const float*)d_in[5];
  const float* cpb_b1      = (const float*)d_in[6];
  const float* cpb_w2      = (const float*)d_in[7];
  const float* proj_w      = (const float*)d_in[8];
  const float* proj_b      = (const float*)d_in[9];
  float* out = (float*)d_out;

  char* ws = (char*)d_ws;
  const size_t QKV_B  = 308281344;   // 100352*1536*2
  const size_t XBF_B  = 102760448;   // 100352*512*2
  const size_t WQT_B  = 1572864;     // 1536*512*2
  const size_t PJT_B  = 524288;      // 512*512*2
  const size_t T169_B = 10816;       // 169*16*4
  bf16*  qkv      = (bf16*)ws;
  bf16*  xbf      = (bf16*)(ws + QKV_B);               // also attn_out (aliased)
  bf16*  wqkvT    = (bf16*)(ws + QKV_B + XBF_B);
  bf16*  projT    = (bf16*)(ws + QKV_B + XBF_B + WQT_B);
  float* tab169   = (float*)(ws + QKV_B + XBF_B + WQT_B + PJT_B);
  float* bias_sig = (float*)(ws + QKV_B + XBF_B + WQT_B + PJT_B + T169_B);

  cvt_x<<<2048, 256, 0, stream>>>(x, xbf, MROWS * 512 / 4);
  transpose_bf16<<<3072, 256, 0, stream>>>(w_qkv, wqkvT, 512, 1536);
  transpose_bf16<<<1024, 256, 0, stream>>>(proj_w, projT, 512, 512);
  cpb_mlp<<<169, 64, 0, stream>>>(cpb_w1, cpb_b1, cpb_w2, tab169);
  bias_expand<<<208, 256, 0, stream>>>(tab169, bias_sig);

  gemm_bt<0><<<dim3(784, 12), 256, 0, stream>>>(xbf, wqkvT, qkv, q_bias, v_bias,
                                                MROWS, 1536, 512);
  attn_mfma<<<8192, 256, 0, stream>>>(qkv, bias_sig, logit_scale, xbf);
  gemm_bt<1><<<dim3(784, 4), 256, 0, stream>>>(xbf, projT, out, proj_b, nullptr,
                                               MROWS, 512, 512);
}